// Round 4
// baseline (1445.787 us; speedup 1.0000x reference)
//
#include <hip/hip_runtime.h>
#include <cstdint>
#include <cstddef>

#define D 1024
#define LSEQ 2048
#define BATCH 8
#define NCHUNK 32   // LSEQ / 64

typedef float fx4  __attribute__((ext_vector_type(4)));
typedef short s16x8 __attribute__((ext_vector_type(8)));
typedef short s16x4 __attribute__((ext_vector_type(4)));

static __device__ __forceinline__ short f2bf(float f) {
  unsigned u = __builtin_bit_cast(unsigned, f);
  u = (u + 0x7FFFu + ((u >> 16) & 1u)) >> 16;   // RNE (finite values)
  return (short)u;
}
static __device__ __forceinline__ float bf2f(unsigned short h) {
  unsigned u = ((unsigned)h) << 16;
  return __builtin_bit_cast(float, u);
}

// ---------------------------------------------------------------------------
// pack fp32 -> bf16 (grid-stride, 8 elems/thread/iter)
// ---------------------------------------------------------------------------
__global__ __launch_bounds__(256)
void pack_bf16(const float* __restrict__ in, short* __restrict__ outp, int n8) {
  int i = blockIdx.x * 256 + threadIdx.x;
  const int stride = gridDim.x * 256;
  for (; i < n8; i += stride) {
    const float* p = in + (size_t)i * 8;
    s16x8 o;
#pragma unroll
    for (int j = 0; j < 8; ++j) o[j] = f2bf(p[j]);
    *(s16x8*)(outp + (size_t)i * 8) = o;
  }
}

// ---------------------------------------------------------------------------
// W [K][N] fp32 -> WT [N][K] bf16, 64x64 tiles via LDS
// ---------------------------------------------------------------------------
__global__ __launch_bounds__(256)
void wtrans(const float* __restrict__ W, short* __restrict__ WT) {
  __shared__ short Tl[64][66];
  const int nt = blockIdx.x, kt0 = blockIdx.y;
  const int tid = threadIdx.x;
  const int c = (tid & 15) * 4, r = tid >> 4;
#pragma unroll
  for (int p = 0; p < 4; ++p) {
    const int krow = r + p * 16;
    float4 v4 = *(const float4*)&W[(size_t)(kt0 * 64 + krow) * D + nt * 64 + c];
    Tl[c + 0][krow] = f2bf(v4.x);
    Tl[c + 1][krow] = f2bf(v4.y);
    Tl[c + 2][krow] = f2bf(v4.z);
    Tl[c + 3][krow] = f2bf(v4.w);
  }
  __syncthreads();
#pragma unroll
  for (int p = 0; p < 4; ++p) {
    const int n = r + p * 16;
    s16x4 o4;
#pragma unroll
    for (int j = 0; j < 4; ++j) o4[j] = Tl[n][c + j];
    *(s16x4*)(WT + (size_t)(nt * 64 + n) * D + kt0 * 64 + c) = o4;
  }
}

// ---------------------------------------------------------------------------
// bf16 MFMA projection GEMM (unchanged from round 3)
// ---------------------------------------------------------------------------
__global__ __launch_bounds__(256)
void proj_mfma(const short* __restrict__ A, const short* __restrict__ Bt,
               short* __restrict__ OUT, int mode, float scale) {
  __shared__ short As[2][4096];
  __shared__ short Bs[2][4096];
  const int tid = threadIdx.x;
  const int l = tid & 63, w = tid >> 6;
  const int lo = l & 15, hi = l >> 4;
  const int wm = w >> 1, wn = w & 1;
  const int row0 = blockIdx.x * 128, col0 = blockIdx.y * 128;

#define STAGE(nb, ktn)                                                          \
  {                                                                             \
    const short* ga0 = A + ((size_t)(row0 + l) * D + (ktn) + w * 8);            \
    const short* gb0 = Bt + ((size_t)(col0 + l) * D + (ktn) + w * 8);           \
    __builtin_amdgcn_global_load_lds(                                           \
        (const __attribute__((address_space(1))) void*)ga0,                     \
        (__attribute__((address_space(3))) void*)&As[nb][(w * 128) * 8], 16, 0, 0); \
    __builtin_amdgcn_global_load_lds(                                           \
        (const __attribute__((address_space(1))) void*)(ga0 + 64 * D),          \
        (__attribute__((address_space(3))) void*)&As[nb][(w * 128 + 64) * 8], 16, 0, 0); \
    __builtin_amdgcn_global_load_lds(                                           \
        (const __attribute__((address_space(1))) void*)gb0,                     \
        (__attribute__((address_space(3))) void*)&Bs[nb][(w * 128) * 8], 16, 0, 0); \
    __builtin_amdgcn_global_load_lds(                                           \
        (const __attribute__((address_space(1))) void*)(gb0 + 64 * D),          \
        (__attribute__((address_space(3))) void*)&Bs[nb][(w * 128 + 64) * 8], 16, 0, 0); \
  }

  fx4 acc[4][4];
#pragma unroll
  for (int i = 0; i < 4; ++i)
#pragma unroll
    for (int j = 0; j < 4; ++j) acc[i][j] = (fx4){0.f, 0.f, 0.f, 0.f};

  STAGE(0, 0);
  __syncthreads();
  int cur = 0;
  for (int kt = 0; kt < D; kt += 32) {
    if (kt + 32 < D) STAGE(cur ^ 1, kt + 32);
    s16x8 af[4], bfr[4];
#pragma unroll
    for (int mt = 0; mt < 4; ++mt)
      af[mt] = *(const s16x8*)&As[cur][(hi * 128 + wm * 64 + mt * 16 + lo) * 8];
#pragma unroll
    for (int nt = 0; nt < 4; ++nt)
      bfr[nt] = *(const s16x8*)&Bs[cur][(hi * 128 + wn * 64 + nt * 16 + lo) * 8];
#pragma unroll
    for (int mt = 0; mt < 4; ++mt)
#pragma unroll
      for (int nt = 0; nt < 4; ++nt)
        acc[mt][nt] = __builtin_amdgcn_mfma_f32_16x16x32_bf16(af[mt], bfr[nt], acc[mt][nt], 0, 0, 0);
    __syncthreads();
    cur ^= 1;
  }
#undef STAGE

#pragma unroll
  for (int mt = 0; mt < 4; ++mt)
#pragma unroll
    for (int nt = 0; nt < 4; ++nt) {
      const size_t rbase = (size_t)(row0 + wm * 64 + mt * 16 + hi * 4);
      const int col = col0 + wn * 64 + nt * 16 + lo;
#pragma unroll
      for (int r = 0; r < 4; ++r) {
        float val = acc[mt][nt][r];
        if (mode == 0) val *= scale;
        else if (mode == 2) val = val / (1.f + expf(-val));
        OUT[(rbase + r) * D + col] = f2bf(val);
      }
    }
}

// ---------------------------------------------------------------------------
// k row L2-normalize, bf16 in place. One wave per row.
// ---------------------------------------------------------------------------
__global__ __launch_bounds__(256)
void knormb(short* __restrict__ kk) {
  const int lane = threadIdx.x & 63;
  const int w = threadIdx.x >> 6;
  const size_t row = (size_t)blockIdx.x * 4 + w;
  s16x8 v0 = *(const s16x8*)&kk[row * D + lane * 8];
  s16x8 v1 = *(const s16x8*)&kk[row * D + 512 + lane * 8];
  float f[16];
  float ss = 0.f;
#pragma unroll
  for (int j = 0; j < 8; ++j) {
    f[j] = bf2f((unsigned short)v0[j]);
    f[8 + j] = bf2f((unsigned short)v1[j]);
  }
#pragma unroll
  for (int j = 0; j < 16; ++j) ss += f[j] * f[j];
#pragma unroll
  for (int d = 1; d < 64; d <<= 1) ss += __shfl_xor(ss, d, 64);
  const float s = 1.f / fmaxf(sqrtf(ss), 1e-12f);
  s16x8 o0, o1;
#pragma unroll
  for (int j = 0; j < 8; ++j) {
    o0[j] = f2bf(f[j] * s);
    o1[j] = f2bf(f[8 + j] * s);
  }
  *(s16x8*)&kk[row * D + lane * 8] = o0;
  *(s16x8*)&kk[row * D + 512 + lane * 8] = o1;
}

// ---------------------------------------------------------------------------
// transpose kh [b][L][D] -> kT [b][D][L] (bf16), 64x64 tiles via LDS
// ---------------------------------------------------------------------------
__global__ __launch_bounds__(256)
void transpose_bf16(const short* __restrict__ kh, short* __restrict__ kT) {
  __shared__ short Tl[64][66];
  const int dt = blockIdx.x, lt = blockIdx.y, b = blockIdx.z;
  const int tid = threadIdx.x;
  const int c = (tid & 15) * 4, r = tid >> 4;
#pragma unroll
  for (int p = 0; p < 4; ++p) {
    const int row = r + p * 16;
    s16x4 v4 = *(const s16x4*)(kh + ((size_t)b * LSEQ + lt * 64 + row) * D + dt * 64 + c);
#pragma unroll
    for (int j = 0; j < 4; ++j) Tl[c + j][row] = v4[j];
  }
  __syncthreads();
#pragma unroll
  for (int p = 0; p < 4; ++p) {
    const int dk = r + p * 16;
    s16x4 o4;
#pragma unroll
    for (int j = 0; j < 4; ++j) o4[j] = Tl[dk][c + j];
    *(s16x4*)(kT + ((size_t)b * D + dt * 64 + dk) * LSEQ + lt * 64 + c) = o4;
  }
}

// ---------------------------------------------------------------------------
// beta[row] = sigmoid( dot(x_row, Wb) ). fp32 exact.
// ---------------------------------------------------------------------------
__global__ __launch_bounds__(256)
void beta_kernel(const float* __restrict__ x, const float* __restrict__ Wb,
                 float* __restrict__ beta) {
  const int lane = threadIdx.x & 63;
  const int w = threadIdx.x >> 6;
  const size_t row = (size_t)blockIdx.x * 4 + w;
  float s = 0.f;
#pragma unroll
  for (int m = 0; m < 4; ++m) {
    float4 xv = *(const float4*)&x[row * D + m * 256 + lane * 4];
    float4 wv = *(const float4*)&Wb[m * 256 + lane * 4];
    s += xv.x * wv.x + xv.y * wv.y + xv.z * wv.z + xv.w * wv.w;
  }
#pragma unroll
  for (int d = 1; d < 64; d <<= 1) s += __shfl_xor(s, d, 64);
  if (lane == 0) beta[row] = 1.f / (1.f + expf(-s));
}

// ---------------------------------------------------------------------------
// Precompute per chunk (b,t): Minv and Tg (unchanged from round 3)
// ---------------------------------------------------------------------------
__global__ __launch_bounds__(256)
void precompute(const short* __restrict__ qh, const short* __restrict__ kh,
                const float* __restrict__ beta,
                short* __restrict__ Mg, short* __restrict__ Tg) {
  __shared__ float Ash[64 * 65];
  __shared__ float Msh[64 * 65];
  const int tid = threadIdx.x, l = tid & 63, w = tid >> 6;
  const int bt = blockIdx.x;
  const int b = bt >> 5, t = bt & 31;
  const int lo = l & 15, hi = l >> 4;
  const size_t rb = (size_t)b * LSEQ + t * 64;

  fx4 aK[4], aQ[4];
#pragma unroll
  for (int n = 0; n < 4; ++n) { aK[n] = (fx4){0,0,0,0}; aQ[n] = (fx4){0,0,0,0}; }

  const short* krow = kh + (rb + w * 16 + lo) * D;
  const short* qrow = qh + (rb + w * 16 + lo) * D;
#pragma unroll 2
  for (int ks = 0; ks < 32; ++ks) {
    s16x8 ak = *(const s16x8*)(krow + ks * 32 + hi * 8);
    s16x8 aq = *(const s16x8*)(qrow + ks * 32 + hi * 8);
#pragma unroll
    for (int n = 0; n < 4; ++n) {
      s16x8 bk = *(const s16x8*)(kh + (rb + n * 16 + lo) * D + ks * 32 + hi * 8);
      aK[n] = __builtin_amdgcn_mfma_f32_16x16x32_bf16(ak, bk, aK[n], 0, 0, 0);
      aQ[n] = __builtin_amdgcn_mfma_f32_16x16x32_bf16(aq, bk, aQ[n], 0, 0, 0);
    }
  }
#pragma unroll
  for (int n = 0; n < 4; ++n) {
#pragma unroll
    for (int r = 0; r < 4; ++r) {
      const int i = w * 16 + hi * 4 + r, s = n * 16 + lo;
      const float bi = beta[rb + i];
      Ash[i * 65 + s] = (s < i) ? bi * aK[n][r] : 0.f;
      Tg[(size_t)bt * 4096 + i * 64 + s] = (s <= i) ? f2bf(aQ[n][r]) : (short)0;
    }
  }
  __syncthreads();
  if (w == 0) {
    Msh[0 * 65 + l] = (l == 0) ? 1.f : 0.f;
    for (int i = 1; i < 64; ++i) {
      float s = 0.f;
      for (int ss = 0; ss < i; ++ss) s += Ash[i * 65 + ss] * Msh[ss * 65 + l];
      Msh[i * 65 + l] = ((i == l) ? 1.f : 0.f) - s;
    }
  }
  __syncthreads();
  {
    const int row = tid >> 2, c0 = (tid & 3) * 16;
    s16x8 o0, o1;
#pragma unroll
    for (int j = 0; j < 8; ++j) o0[j] = f2bf(Msh[row * 65 + c0 + j]);
#pragma unroll
    for (int j = 0; j < 8; ++j) o1[j] = f2bf(Msh[row * 65 + c0 + 8 + j]);
    *(s16x8*)(Mg + (size_t)bt * 4096 + row * 64 + c0) = o0;
    *(s16x8*)(Mg + (size_t)bt * 4096 + row * 64 + c0 + 8) = o1;
  }
}

// ---------------------------------------------------------------------------
// Sequential chunked scan, v2.
// Grid (8 batches, 64 n-slices) = 512 blocks -> 2 blocks/CU; 4 waves/block.
// blockIdx.x = batch so same-batch blocks land on one XCD (id%8 heuristic).
// Each block owns n-slice of 16 cols. S [1024dk x 16n] fp32 in MFMA regs
// (wave w owns dk in [w*256, w*256+256), 16 fx4 = 64 VGPR).
// SB double-buffered (bf16 [n][dk], XOR-swizzled) -> 3 barriers/chunk.
// A-fragments staged through a 32-entry s16x8 register window X[] reused
// K(t) -> Q(t) -> kT(t) -> K(t+1); loads issue as a batch ahead of MFMAs.
// ---------------------------------------------------------------------------
__global__ __launch_bounds__(256, 2)
void scan_chunked(const short* __restrict__ qh, const short* __restrict__ kh,
                  const short* __restrict__ vh, const short* __restrict__ kT,
                  const float* __restrict__ beta,
                  const short* __restrict__ Mg, const short* __restrict__ Tg,
                  float* __restrict__ out) {
  __shared__ short SB[2][16 * 1024];   // 2 x 32 KB
  __shared__ short RTs[16 * 64];       // rhs^T [n][c]
  __shared__ short UTs[16 * 64];       // U^T   [n][c]
  const int tid = threadIdx.x;
  const int l = tid & 63, w = tid >> 6;
  const int lo = l & 15, hi = l >> 4;
  const int b = blockIdx.x, n0 = blockIdx.y * 16;
  const size_t bL = (size_t)b * LSEQ;
  const int swl = (lo & 7) << 4;
  const int c0 = w * 16 + hi * 4;      // chunk-local row base for P1/P2/P3

#define SBFRAG(buf, ks) \
  (*(const s16x8*)((const char*)SB[buf] + lo * 2048 + ((((ks) * 32 + hi * 8) * 2) ^ swl)))
#define RTFRAG(ks) \
  (*(const s16x8*)((const char*)RTs + lo * 128 + ((((ks) * 32 + hi * 8) * 2) ^ swl)))
#define UTFRAG(ks) \
  (*(const s16x8*)((const char*)UTs + lo * 128 + ((((ks) * 32 + hi * 8) * 2) ^ swl)))

  fx4 S[16];
#pragma unroll
  for (int mt = 0; mt < 16; ++mt) S[mt] = (fx4){0.f, 0.f, 0.f, 0.f};

  s16x8 X[32];
  // preload K fragments for chunk 0
  {
    const short* Ak = kh + (bL + w * 16 + lo) * D;
#pragma unroll
    for (int ks = 0; ks < 32; ++ks) X[ks] = *(const s16x8*)(Ak + ks * 32 + hi * 8);
  }
  // zero SB[0]
  for (int i = tid; i < 16 * 1024 / 2; i += 256) ((int*)SB[0])[i] = 0;
  __syncthreads();

  int cur = 0;
  for (int t = 0; t < NCHUNK; ++t) {
    const int r0 = t * 64;
    // ---- small prefetches (consumed after P1 / in P2 / in P3)
    float vv[4], bb[4];
#pragma unroll
    for (int r = 0; r < 4; ++r) {
      vv[r] = bf2f((unsigned short)vh[(bL + r0 + c0 + r) * D + n0 + lo]);
      bb[r] = beta[bL + r0 + c0 + r];
    }
    const size_t mtb = ((size_t)(b * NCHUNK + t)) * 4096 + (w * 16 + lo) * 64;
    const s16x8 mg0 = *(const s16x8*)(Mg + mtb + hi * 8);
    const s16x8 mg1 = *(const s16x8*)(Mg + mtb + 32 + hi * 8);
    const s16x8 tg0 = *(const s16x8*)(Tg + mtb + hi * 8);
    const s16x8 tg1 = *(const s16x8*)(Tg + mtb + 32 + hi * 8);

    // ---- P1: R = K_c @ S  (A from X, B from SB[cur]); 2-acc chains
    fx4 a0 = (fx4){0.f, 0.f, 0.f, 0.f}, a1 = (fx4){0.f, 0.f, 0.f, 0.f};
#pragma unroll
    for (int ks = 0; ks < 16; ++ks) {
      a0 = __builtin_amdgcn_mfma_f32_16x16x32_bf16(X[2 * ks], SBFRAG(cur, 2 * ks), a0, 0, 0, 0);
      a1 = __builtin_amdgcn_mfma_f32_16x16x32_bf16(X[2 * ks + 1], SBFRAG(cur, 2 * ks + 1), a1, 0, 0, 0);
    }
    // issue Q loads into X (consumed in P3; latency covered by rhs/bar1/P2/bar2)
    {
      const short* Aq = qh + (bL + r0 + w * 16 + lo) * D;
#pragma unroll
      for (int ks = 0; ks < 32; ++ks) X[ks] = *(const s16x8*)(Aq + ks * 32 + hi * 8);
    }
    {
      const fx4 acc = a0 + a1;
      s16x4 pk;
#pragma unroll
      for (int r = 0; r < 4; ++r) pk[r] = f2bf(bb[r] * (vv[r] - acc[r]));
      *(s16x4*)((char*)RTs + lo * 128 + ((c0 * 2) ^ swl)) = pk;
    }
    __syncthreads();   // bar1: RTs ready

    // ---- P2: U = Minv @ rhs
    {
      fx4 u = (fx4){0.f, 0.f, 0.f, 0.f};
      u = __builtin_amdgcn_mfma_f32_16x16x32_bf16(mg0, RTFRAG(0), u, 0, 0, 0);
      u = __builtin_amdgcn_mfma_f32_16x16x32_bf16(mg1, RTFRAG(1), u, 0, 0, 0);
      s16x4 pk;
#pragma unroll
      for (int r = 0; r < 4; ++r) pk[r] = f2bf(u[r]);
      *(s16x4*)((char*)UTs + lo * 128 + ((c0 * 2) ^ swl)) = pk;
    }
    __syncthreads();   // bar2: UTs ready

    const s16x8 bu0 = UTFRAG(0), bu1 = UTFRAG(1);

    // ---- P3: O = Q_c @ S(old) + trilQK @ U
    {
      a0 = (fx4){0.f, 0.f, 0.f, 0.f}; a1 = (fx4){0.f, 0.f, 0.f, 0.f};
#pragma unroll
      for (int ks = 0; ks < 16; ++ks) {
        a0 = __builtin_amdgcn_mfma_f32_16x16x32_bf16(X[2 * ks], SBFRAG(cur, 2 * ks), a0, 0, 0, 0);
        a1 = __builtin_amdgcn_mfma_f32_16x16x32_bf16(X[2 * ks + 1], SBFRAG(cur, 2 * ks + 1), a1, 0, 0, 0);
      }
      fx4 o = a0 + a1;
      o = __builtin_amdgcn_mfma_f32_16x16x32_bf16(tg0, bu0, o, 0, 0, 0);
      o = __builtin_amdgcn_mfma_f32_16x16x32_bf16(tg1, bu1, o, 0, 0, 0);
#pragma unroll
      for (int r = 0; r < 4; ++r)
        out[(bL + r0 + c0 + r) * D + n0 + lo] = o[r];
    }

    // ---- P4: S += K_c^T @ U  (A from kT via X window)
    {
      const short* KTb = kT + ((size_t)b * D + w * 256 + lo) * LSEQ + r0;
#pragma unroll
      for (int mt = 0; mt < 16; ++mt) {
        X[2 * mt]     = *(const s16x8*)(KTb + (size_t)mt * 16 * LSEQ + hi * 8);
        X[2 * mt + 1] = *(const s16x8*)(KTb + (size_t)mt * 16 * LSEQ + 32 + hi * 8);
      }
#pragma unroll
      for (int mt = 0; mt < 16; ++mt) {
        S[mt] = __builtin_amdgcn_mfma_f32_16x16x32_bf16(X[2 * mt], bu0, S[mt], 0, 0, 0);
        S[mt] = __builtin_amdgcn_mfma_f32_16x16x32_bf16(X[2 * mt + 1], bu1, S[mt], 0, 0, 0);
      }
    }

    // issue K loads for chunk t+1 (covered by P5 + bar3)
    if (t + 1 < NCHUNK) {
      const short* Ak = kh + (bL + r0 + 64 + w * 16 + lo) * D;
#pragma unroll
      for (int ks = 0; ks < 32; ++ks) X[ks] = *(const s16x8*)(Ak + ks * 32 + hi * 8);
    }

    // ---- P5: SB[cur^1] = bf16(S)
#pragma unroll
    for (int mt = 0; mt < 16; ++mt) {
      const int dk0 = w * 256 + mt * 16 + hi * 4;
      s16x4 pk;
#pragma unroll
      for (int r = 0; r < 4; ++r) pk[r] = f2bf(S[mt][r]);
      *(s16x4*)((char*)SB[cur ^ 1] + lo * 2048 + ((dk0 * 2) ^ swl)) = pk;
    }
    __syncthreads();   // bar3: new SB ready; all reads of old buffers done
    cur ^= 1;
  }
#undef SBFRAG
#undef RTFRAG
#undef UTFRAG
}

// ---------------------------------------------------------------------------
// LayerNorm in place on out. One wave per row.
// ---------------------------------------------------------------------------
__global__ __launch_bounds__(256)
void ln_kernel(float* __restrict__ o, const float* __restrict__ gamma,
               const float* __restrict__ betap) {
  const int lane = threadIdx.x & 63;
  const int w = threadIdx.x >> 6;
  const size_t row = (size_t)blockIdx.x * 4 + w;
  float4 vals[4];
  float s = 0.f;
#pragma unroll
  for (int m = 0; m < 4; ++m) {
    vals[m] = *(const float4*)&o[row * D + m * 256 + lane * 4];
    s += (vals[m].x + vals[m].y) + (vals[m].z + vals[m].w);
  }
#pragma unroll
  for (int d = 1; d < 64; d <<= 1) s += __shfl_xor(s, d, 64);
  const float mu = s * (1.f / 1024.f);
  float vs = 0.f;
#pragma unroll
  for (int m = 0; m < 4; ++m) {
    float dx = vals[m].x - mu; vs += dx * dx;
    dx = vals[m].y - mu; vs += dx * dx;
    dx = vals[m].z - mu; vs += dx * dx;
    dx = vals[m].w - mu; vs += dx * dx;
  }
#pragma unroll
  for (int d = 1; d < 64; d <<= 1) vs += __shfl_xor(vs, d, 64);
  const float r = 1.f / sqrtf(vs * (1.f / 1024.f) + 1e-5f);
#pragma unroll
  for (int m = 0; m < 4; ++m) {
    const int dbase = m * 256 + lane * 4;
    float4 g4 = *(const float4*)&gamma[dbase];
    float4 b4 = *(const float4*)&betap[dbase];
    float4 y;
    y.x = (vals[m].x - mu) * r * g4.x + b4.x;
    y.y = (vals[m].y - mu) * r * g4.y + b4.y;
    y.z = (vals[m].z - mu) * r * g4.z + b4.z;
    y.w = (vals[m].w - mu) * r * g4.w + b4.w;
    *(float4*)&o[row * D + dbase] = y;
  }
}

// ---------------------------------------------------------------------------
extern "C" void kernel_launch(void* const* d_in, const int* in_sizes, int n_in,
                              void* d_out, int out_size, void* d_ws, size_t ws_size,
                              hipStream_t stream) {
  const float* x   = (const float*)d_in[0];
  const float* Wq  = (const float*)d_in[1];
  const float* Wk  = (const float*)d_in[2];
  const float* Wv  = (const float*)d_in[3];
  const float* Wb  = (const float*)d_in[4];
  const float* lng = (const float*)d_in[5];
  const float* lnb = (const float*)d_in[6];
  float* out = (float*)d_out;

  const size_t MB = 1ull << 20;
  char* wsb = (char*)d_ws;
  float* beta = (float*)wsb;                 // 64 KB
  short* Mg   = (short*)(wsb + 1 * MB);      // 2 MB
  short* Tg   = (short*)(wsb + 4 * MB);      // 2 MB
  short* WTq  = (short*)(wsb + 6 * MB);      // 2 MB
  short* WTk  = (short*)(wsb + 8 * MB);      // 2 MB
  short* WTv  = (short*)(wsb + 10 * MB);     // 2 MB
  short* xh   = (short*)(wsb + 16 * MB);     // 32 MB
  short* qh   = (short*)(wsb + 64 * MB);     // 32 MB
  short* kh   = (short*)(wsb + 96 * MB);
  short* vh   = (short*)(wsb + 128 * MB);
  short* kT   = (short*)(wsb + 160 * MB);

  const int N8 = (BATCH * LSEQ * D) / 8;
  const dim3 pg(128, 8);

  pack_bf16<<<2048, 256, 0, stream>>>(x, xh, N8);
  wtrans<<<dim3(16, 16), 256, 0, stream>>>(Wq, WTq);
  wtrans<<<dim3(16, 16), 256, 0, stream>>>(Wk, WTk);
  wtrans<<<dim3(16, 16), 256, 0, stream>>>(Wv, WTv);

  proj_mfma<<<pg, 256, 0, stream>>>(xh, WTq, qh, 0, 0.03125f);
  proj_mfma<<<pg, 256, 0, stream>>>(xh, WTk, kh, 1, 1.f);
  proj_mfma<<<pg, 256, 0, stream>>>(xh, WTv, vh, 2, 1.f);

  knormb<<<4096, 256, 0, stream>>>(kh);
  transpose_bf16<<<dim3(16, 32, 8), 256, 0, stream>>>(kh, kT);
  beta_kernel<<<4096, 256, 0, stream>>>(x, Wb, beta);

  precompute<<<256, 256, 0, stream>>>(qh, kh, beta, Mg, Tg);
  scan_chunked<<<dim3(8, 64), 256, 0, stream>>>(qh, kh, vh, kT, beta, Mg, Tg, out);
  ln_kernel<<<4096, 256, 0, stream>>>(out, lng, lnb);
}

// Round 5
// 1087.201 us; speedup vs baseline: 1.3298x; 1.3298x over previous
//
#include <hip/hip_runtime.h>
#include <cstdint>
#include <cstddef>

#define D 1024
#define LSEQ 2048
#define BATCH 8
#define NCHUNK 32   // LSEQ / 64

typedef float fx4  __attribute__((ext_vector_type(4)));
typedef short s16x8 __attribute__((ext_vector_type(8)));
typedef short s16x4 __attribute__((ext_vector_type(4)));

static __device__ __forceinline__ short f2bf(float f) {
  unsigned u = __builtin_bit_cast(unsigned, f);
  u = (u + 0x7FFFu + ((u >> 16) & 1u)) >> 16;   // RNE (finite values)
  return (short)u;
}
static __device__ __forceinline__ float bf2f(unsigned short h) {
  unsigned u = ((unsigned)h) << 16;
  return __builtin_bit_cast(float, u);
}

// ---------------------------------------------------------------------------
// pack fp32 -> bf16 (grid-stride, 8 elems/thread/iter)
// ---------------------------------------------------------------------------
__global__ __launch_bounds__(256)
void pack_bf16(const float* __restrict__ in, short* __restrict__ outp, int n8) {
  int i = blockIdx.x * 256 + threadIdx.x;
  const int stride = gridDim.x * 256;
  for (; i < n8; i += stride) {
    const float* p = in + (size_t)i * 8;
    s16x8 o;
#pragma unroll
    for (int j = 0; j < 8; ++j) o[j] = f2bf(p[j]);
    *(s16x8*)(outp + (size_t)i * 8) = o;
  }
}

// ---------------------------------------------------------------------------
// W [K][N] fp32 -> WT [N][K] bf16, 64x64 tiles via LDS
// ---------------------------------------------------------------------------
__global__ __launch_bounds__(256)
void wtrans(const float* __restrict__ W, short* __restrict__ WT) {
  __shared__ short Tl[64][66];
  const int nt = blockIdx.x, kt0 = blockIdx.y;
  const int tid = threadIdx.x;
  const int c = (tid & 15) * 4, r = tid >> 4;
#pragma unroll
  for (int p = 0; p < 4; ++p) {
    const int krow = r + p * 16;
    float4 v4 = *(const float4*)&W[(size_t)(kt0 * 64 + krow) * D + nt * 64 + c];
    Tl[c + 0][krow] = f2bf(v4.x);
    Tl[c + 1][krow] = f2bf(v4.y);
    Tl[c + 2][krow] = f2bf(v4.z);
    Tl[c + 3][krow] = f2bf(v4.w);
  }
  __syncthreads();
#pragma unroll
  for (int p = 0; p < 4; ++p) {
    const int n = r + p * 16;
    s16x4 o4;
#pragma unroll
    for (int j = 0; j < 4; ++j) o4[j] = Tl[n][c + j];
    *(s16x4*)(WT + (size_t)(nt * 64 + n) * D + kt0 * 64 + c) = o4;
  }
}

// ---------------------------------------------------------------------------
// bf16 MFMA projection GEMM (unchanged from round 3)
// ---------------------------------------------------------------------------
__global__ __launch_bounds__(256)
void proj_mfma(const short* __restrict__ A, const short* __restrict__ Bt,
               short* __restrict__ OUT, int mode, float scale) {
  __shared__ short As[2][4096];
  __shared__ short Bs[2][4096];
  const int tid = threadIdx.x;
  const int l = tid & 63, w = tid >> 6;
  const int lo = l & 15, hi = l >> 4;
  const int wm = w >> 1, wn = w & 1;
  const int row0 = blockIdx.x * 128, col0 = blockIdx.y * 128;

#define STAGE(nb, ktn)                                                          \
  {                                                                             \
    const short* ga0 = A + ((size_t)(row0 + l) * D + (ktn) + w * 8);            \
    const short* gb0 = Bt + ((size_t)(col0 + l) * D + (ktn) + w * 8);           \
    __builtin_amdgcn_global_load_lds(                                           \
        (const __attribute__((address_space(1))) void*)ga0,                     \
        (__attribute__((address_space(3))) void*)&As[nb][(w * 128) * 8], 16, 0, 0); \
    __builtin_amdgcn_global_load_lds(                                           \
        (const __attribute__((address_space(1))) void*)(ga0 + 64 * D),          \
        (__attribute__((address_space(3))) void*)&As[nb][(w * 128 + 64) * 8], 16, 0, 0); \
    __builtin_amdgcn_global_load_lds(                                           \
        (const __attribute__((address_space(1))) void*)gb0,                     \
        (__attribute__((address_space(3))) void*)&Bs[nb][(w * 128) * 8], 16, 0, 0); \
    __builtin_amdgcn_global_load_lds(                                           \
        (const __attribute__((address_space(1))) void*)(gb0 + 64 * D),          \
        (__attribute__((address_space(3))) void*)&Bs[nb][(w * 128 + 64) * 8], 16, 0, 0); \
  }

  fx4 acc[4][4];
#pragma unroll
  for (int i = 0; i < 4; ++i)
#pragma unroll
    for (int j = 0; j < 4; ++j) acc[i][j] = (fx4){0.f, 0.f, 0.f, 0.f};

  STAGE(0, 0);
  __syncthreads();
  int cur = 0;
  for (int kt = 0; kt < D; kt += 32) {
    if (kt + 32 < D) STAGE(cur ^ 1, kt + 32);
    s16x8 af[4], bfr[4];
#pragma unroll
    for (int mt = 0; mt < 4; ++mt)
      af[mt] = *(const s16x8*)&As[cur][(hi * 128 + wm * 64 + mt * 16 + lo) * 8];
#pragma unroll
    for (int nt = 0; nt < 4; ++nt)
      bfr[nt] = *(const s16x8*)&Bs[cur][(hi * 128 + wn * 64 + nt * 16 + lo) * 8];
#pragma unroll
    for (int mt = 0; mt < 4; ++mt)
#pragma unroll
      for (int nt = 0; nt < 4; ++nt)
        acc[mt][nt] = __builtin_amdgcn_mfma_f32_16x16x32_bf16(af[mt], bfr[nt], acc[mt][nt], 0, 0, 0);
    __syncthreads();
    cur ^= 1;
  }
#undef STAGE

#pragma unroll
  for (int mt = 0; mt < 4; ++mt)
#pragma unroll
    for (int nt = 0; nt < 4; ++nt) {
      const size_t rbase = (size_t)(row0 + wm * 64 + mt * 16 + hi * 4);
      const int col = col0 + wn * 64 + nt * 16 + lo;
#pragma unroll
      for (int r = 0; r < 4; ++r) {
        float val = acc[mt][nt][r];
        if (mode == 0) val *= scale;
        else if (mode == 2) val = val / (1.f + expf(-val));
        OUT[(rbase + r) * D + col] = f2bf(val);
      }
    }
}

// ---------------------------------------------------------------------------
// k row L2-normalize, bf16 in place. One wave per row.
// ---------------------------------------------------------------------------
__global__ __launch_bounds__(256)
void knormb(short* __restrict__ kk) {
  const int lane = threadIdx.x & 63;
  const int w = threadIdx.x >> 6;
  const size_t row = (size_t)blockIdx.x * 4 + w;
  s16x8 v0 = *(const s16x8*)&kk[row * D + lane * 8];
  s16x8 v1 = *(const s16x8*)&kk[row * D + 512 + lane * 8];
  float f[16];
  float ss = 0.f;
#pragma unroll
  for (int j = 0; j < 8; ++j) {
    f[j] = bf2f((unsigned short)v0[j]);
    f[8 + j] = bf2f((unsigned short)v1[j]);
  }
#pragma unroll
  for (int j = 0; j < 16; ++j) ss += f[j] * f[j];
#pragma unroll
  for (int d = 1; d < 64; d <<= 1) ss += __shfl_xor(ss, d, 64);
  const float s = 1.f / fmaxf(sqrtf(ss), 1e-12f);
  s16x8 o0, o1;
#pragma unroll
  for (int j = 0; j < 8; ++j) {
    o0[j] = f2bf(f[j] * s);
    o1[j] = f2bf(f[8 + j] * s);
  }
  *(s16x8*)&kk[row * D + lane * 8] = o0;
  *(s16x8*)&kk[row * D + 512 + lane * 8] = o1;
}

// ---------------------------------------------------------------------------
// transpose kh [b][L][D] -> kT [b][D][L] (bf16), 64x64 tiles via LDS
// ---------------------------------------------------------------------------
__global__ __launch_bounds__(256)
void transpose_bf16(const short* __restrict__ kh, short* __restrict__ kT) {
  __shared__ short Tl[64][66];
  const int dt = blockIdx.x, lt = blockIdx.y, b = blockIdx.z;
  const int tid = threadIdx.x;
  const int c = (tid & 15) * 4, r = tid >> 4;
#pragma unroll
  for (int p = 0; p < 4; ++p) {
    const int row = r + p * 16;
    s16x4 v4 = *(const s16x4*)(kh + ((size_t)b * LSEQ + lt * 64 + row) * D + dt * 64 + c);
#pragma unroll
    for (int j = 0; j < 4; ++j) Tl[c + j][row] = v4[j];
  }
  __syncthreads();
#pragma unroll
  for (int p = 0; p < 4; ++p) {
    const int dk = r + p * 16;
    s16x4 o4;
#pragma unroll
    for (int j = 0; j < 4; ++j) o4[j] = Tl[dk][c + j];
    *(s16x4*)(kT + ((size_t)b * D + dt * 64 + dk) * LSEQ + lt * 64 + c) = o4;
  }
}

// ---------------------------------------------------------------------------
// beta[row] = sigmoid( dot(x_row, Wb) ). fp32 exact.
// ---------------------------------------------------------------------------
__global__ __launch_bounds__(256)
void beta_kernel(const float* __restrict__ x, const float* __restrict__ Wb,
                 float* __restrict__ beta) {
  const int lane = threadIdx.x & 63;
  const int w = threadIdx.x >> 6;
  const size_t row = (size_t)blockIdx.x * 4 + w;
  float s = 0.f;
#pragma unroll
  for (int m = 0; m < 4; ++m) {
    float4 xv = *(const float4*)&x[row * D + m * 256 + lane * 4];
    float4 wv = *(const float4*)&Wb[m * 256 + lane * 4];
    s += xv.x * wv.x + xv.y * wv.y + xv.z * wv.z + xv.w * wv.w;
  }
#pragma unroll
  for (int d = 1; d < 64; d <<= 1) s += __shfl_xor(s, d, 64);
  if (lane == 0) beta[row] = 1.f / (1.f + expf(-s));
}

// ---------------------------------------------------------------------------
// Precompute per chunk (b,t): Minv and Tg (unchanged from round 3)
// ---------------------------------------------------------------------------
__global__ __launch_bounds__(256)
void precompute(const short* __restrict__ qh, const short* __restrict__ kh,
                const float* __restrict__ beta,
                short* __restrict__ Mg, short* __restrict__ Tg) {
  __shared__ float Ash[64 * 65];
  __shared__ float Msh[64 * 65];
  const int tid = threadIdx.x, l = tid & 63, w = tid >> 6;
  const int bt = blockIdx.x;
  const int b = bt >> 5, t = bt & 31;
  const int lo = l & 15, hi = l >> 4;
  const size_t rb = (size_t)b * LSEQ + t * 64;

  fx4 aK[4], aQ[4];
#pragma unroll
  for (int n = 0; n < 4; ++n) { aK[n] = (fx4){0,0,0,0}; aQ[n] = (fx4){0,0,0,0}; }

  const short* krow = kh + (rb + w * 16 + lo) * D;
  const short* qrow = qh + (rb + w * 16 + lo) * D;
#pragma unroll 2
  for (int ks = 0; ks < 32; ++ks) {
    s16x8 ak = *(const s16x8*)(krow + ks * 32 + hi * 8);
    s16x8 aq = *(const s16x8*)(qrow + ks * 32 + hi * 8);
#pragma unroll
    for (int n = 0; n < 4; ++n) {
      s16x8 bk = *(const s16x8*)(kh + (rb + n * 16 + lo) * D + ks * 32 + hi * 8);
      aK[n] = __builtin_amdgcn_mfma_f32_16x16x32_bf16(ak, bk, aK[n], 0, 0, 0);
      aQ[n] = __builtin_amdgcn_mfma_f32_16x16x32_bf16(aq, bk, aQ[n], 0, 0, 0);
    }
  }
#pragma unroll
  for (int n = 0; n < 4; ++n) {
#pragma unroll
    for (int r = 0; r < 4; ++r) {
      const int i = w * 16 + hi * 4 + r, s = n * 16 + lo;
      const float bi = beta[rb + i];
      Ash[i * 65 + s] = (s < i) ? bi * aK[n][r] : 0.f;
      Tg[(size_t)bt * 4096 + i * 64 + s] = (s <= i) ? f2bf(aQ[n][r]) : (short)0;
    }
  }
  __syncthreads();
  if (w == 0) {
    Msh[0 * 65 + l] = (l == 0) ? 1.f : 0.f;
    for (int i = 1; i < 64; ++i) {
      float s = 0.f;
      for (int ss = 0; ss < i; ++ss) s += Ash[i * 65 + ss] * Msh[ss * 65 + l];
      Msh[i * 65 + l] = ((i == l) ? 1.f : 0.f) - s;
    }
  }
  __syncthreads();
  {
    const int row = tid >> 2, c0 = (tid & 3) * 16;
    s16x8 o0, o1;
#pragma unroll
    for (int j = 0; j < 8; ++j) o0[j] = f2bf(Msh[row * 65 + c0 + j]);
#pragma unroll
    for (int j = 0; j < 8; ++j) o1[j] = f2bf(Msh[row * 65 + c0 + 8 + j]);
    *(s16x8*)(Mg + (size_t)bt * 4096 + row * 64 + c0) = o0;
    *(s16x8*)(Mg + (size_t)bt * 4096 + row * 64 + c0 + 8) = o1;
  }
}

// ---------------------------------------------------------------------------
// Sequential chunked scan, v3.
// Grid (8 batches, 64 n-slices), 4 waves, 2 blocks/CU.
// v2's spill bug fixed: no persistent 32-fragment register window. Fragment
// loads happen in 8-deep groups local to each phase ({load 8, mfma 8} x4,
// fully unrolled) so the compiler overlaps group g+1 loads with group g
// MFMAs while register liveness stays ~2 groups (64 VGPR).
// ---------------------------------------------------------------------------
__global__ __launch_bounds__(256, 2)
void scan_chunked(const short* __restrict__ qh, const short* __restrict__ kh,
                  const short* __restrict__ vh, const short* __restrict__ kT,
                  const float* __restrict__ beta,
                  const short* __restrict__ Mg, const short* __restrict__ Tg,
                  float* __restrict__ out) {
  __shared__ short SB[2][16 * 1024];   // 2 x 32 KB
  __shared__ short RTs[16 * 64];       // rhs^T [n][c]
  __shared__ short UTs[16 * 64];       // U^T   [n][c]
  const int tid = threadIdx.x;
  const int l = tid & 63, w = tid >> 6;
  const int lo = l & 15, hi = l >> 4;
  const int b = blockIdx.x, n0 = blockIdx.y * 16;
  const size_t bL = (size_t)b * LSEQ;
  const int swl = (lo & 7) << 4;
  const int c0 = w * 16 + hi * 4;      // chunk-local row base for P1/P2/P3

#define SBFRAG(buf, ks) \
  (*(const s16x8*)((const char*)SB[buf] + lo * 2048 + ((((ks) * 32 + hi * 8) * 2) ^ swl)))
#define RTFRAG(ks) \
  (*(const s16x8*)((const char*)RTs + lo * 128 + ((((ks) * 32 + hi * 8) * 2) ^ swl)))
#define UTFRAG(ks) \
  (*(const s16x8*)((const char*)UTs + lo * 128 + ((((ks) * 32 + hi * 8) * 2) ^ swl)))

  fx4 S[16];
#pragma unroll
  for (int mt = 0; mt < 16; ++mt) S[mt] = (fx4){0.f, 0.f, 0.f, 0.f};

  // zero SB[0]
  for (int i = tid; i < 16 * 1024 / 2; i += 256) ((int*)SB[0])[i] = 0;
  __syncthreads();

  int cur = 0;
  for (int t = 0; t < NCHUNK; ++t) {
    const int r0 = t * 64;
    // ---- small prefetches (consumed after P1 / in P2 / in P3)
    float vv[4], bb[4];
#pragma unroll
    for (int r = 0; r < 4; ++r) {
      vv[r] = bf2f((unsigned short)vh[(bL + r0 + c0 + r) * D + n0 + lo]);
      bb[r] = beta[bL + r0 + c0 + r];
    }
    const size_t mtb = ((size_t)(b * NCHUNK + t)) * 4096 + (w * 16 + lo) * 64;
    const s16x8 mg0 = *(const s16x8*)(Mg + mtb + hi * 8);
    const s16x8 mg1 = *(const s16x8*)(Mg + mtb + 32 + hi * 8);
    const s16x8 tg0 = *(const s16x8*)(Tg + mtb + hi * 8);
    const s16x8 tg1 = *(const s16x8*)(Tg + mtb + 32 + hi * 8);

    // ---- P1: R = K_c @ S  (A streamed from kh in 8-frag groups, B = SB[cur])
    fx4 a0 = (fx4){0.f, 0.f, 0.f, 0.f}, a1 = (fx4){0.f, 0.f, 0.f, 0.f};
    {
      const short* Ak = kh + (bL + r0 + w * 16 + lo) * D + hi * 8;
#pragma unroll
      for (int g = 0; g < 4; ++g) {
        s16x8 f[8];
#pragma unroll
        for (int i = 0; i < 8; ++i)
          f[i] = *(const s16x8*)(Ak + (g * 8 + i) * 32);
#pragma unroll
        for (int i = 0; i < 8; i += 2) {
          a0 = __builtin_amdgcn_mfma_f32_16x16x32_bf16(f[i],     SBFRAG(cur, g * 8 + i),     a0, 0, 0, 0);
          a1 = __builtin_amdgcn_mfma_f32_16x16x32_bf16(f[i + 1], SBFRAG(cur, g * 8 + i + 1), a1, 0, 0, 0);
        }
      }
    }
    {
      const fx4 acc = a0 + a1;
      s16x4 pk;
#pragma unroll
      for (int r = 0; r < 4; ++r) pk[r] = f2bf(bb[r] * (vv[r] - acc[r]));
      *(s16x4*)((char*)RTs + lo * 128 + ((c0 * 2) ^ swl)) = pk;
    }
    __syncthreads();   // bar1: RTs ready

    // ---- P2: U = Minv @ rhs
    {
      fx4 u = (fx4){0.f, 0.f, 0.f, 0.f};
      u = __builtin_amdgcn_mfma_f32_16x16x32_bf16(mg0, RTFRAG(0), u, 0, 0, 0);
      u = __builtin_amdgcn_mfma_f32_16x16x32_bf16(mg1, RTFRAG(1), u, 0, 0, 0);
      s16x4 pk;
#pragma unroll
      for (int r = 0; r < 4; ++r) pk[r] = f2bf(u[r]);
      *(s16x4*)((char*)UTs + lo * 128 + ((c0 * 2) ^ swl)) = pk;
    }
    __syncthreads();   // bar2: UTs ready

    const s16x8 bu0 = UTFRAG(0), bu1 = UTFRAG(1);

    // ---- P3: O = tril(QK^T) @ U + Q_c @ S(old)
    {
      fx4 o = (fx4){0.f, 0.f, 0.f, 0.f};
      o = __builtin_amdgcn_mfma_f32_16x16x32_bf16(tg0, bu0, o, 0, 0, 0);
      o = __builtin_amdgcn_mfma_f32_16x16x32_bf16(tg1, bu1, o, 0, 0, 0);
      a0 = (fx4){0.f, 0.f, 0.f, 0.f};
      const short* Aq = qh + (bL + r0 + w * 16 + lo) * D + hi * 8;
#pragma unroll
      for (int g = 0; g < 4; ++g) {
        s16x8 f[8];
#pragma unroll
        for (int i = 0; i < 8; ++i)
          f[i] = *(const s16x8*)(Aq + (g * 8 + i) * 32);
#pragma unroll
        for (int i = 0; i < 8; i += 2) {
          o  = __builtin_amdgcn_mfma_f32_16x16x32_bf16(f[i],     SBFRAG(cur, g * 8 + i),     o,  0, 0, 0);
          a0 = __builtin_amdgcn_mfma_f32_16x16x32_bf16(f[i + 1], SBFRAG(cur, g * 8 + i + 1), a0, 0, 0, 0);
        }
      }
      o = o + a0;
#pragma unroll
      for (int r = 0; r < 4; ++r)
        out[(bL + r0 + c0 + r) * D + n0 + lo] = o[r];
    }

    // ---- P4: S += K_c^T @ U  (A streamed from kT in 8-frag groups)
    {
      const short* KTb = kT + ((size_t)b * D + w * 256 + lo) * LSEQ + r0 + hi * 8;
#pragma unroll
      for (int g = 0; g < 4; ++g) {
        s16x8 f[8];
#pragma unroll
        for (int m4 = 0; m4 < 4; ++m4) {
          f[2 * m4]     = *(const s16x8*)(KTb + (size_t)(g * 4 + m4) * 16 * LSEQ);
          f[2 * m4 + 1] = *(const s16x8*)(KTb + (size_t)(g * 4 + m4) * 16 * LSEQ + 32);
        }
#pragma unroll
        for (int m4 = 0; m4 < 4; ++m4) {
          S[g * 4 + m4] = __builtin_amdgcn_mfma_f32_16x16x32_bf16(f[2 * m4],     bu0, S[g * 4 + m4], 0, 0, 0);
          S[g * 4 + m4] = __builtin_amdgcn_mfma_f32_16x16x32_bf16(f[2 * m4 + 1], bu1, S[g * 4 + m4], 0, 0, 0);
        }
      }
    }

    // ---- P5: SB[cur^1] = bf16(S)
#pragma unroll
    for (int mt = 0; mt < 16; ++mt) {
      const int dk0 = w * 256 + mt * 16 + hi * 4;
      s16x4 pk;
#pragma unroll
      for (int r = 0; r < 4; ++r) pk[r] = f2bf(S[mt][r]);
      *(s16x4*)((char*)SB[cur ^ 1] + lo * 2048 + ((dk0 * 2) ^ swl)) = pk;
    }
    __syncthreads();   // bar3: new SB ready; all reads of old buffers done
    cur ^= 1;
  }
#undef SBFRAG
#undef RTFRAG
#undef UTFRAG
}

// ---------------------------------------------------------------------------
// LayerNorm in place on out. One wave per row.
// ---------------------------------------------------------------------------
__global__ __launch_bounds__(256)
void ln_kernel(float* __restrict__ o, const float* __restrict__ gamma,
               const float* __restrict__ betap) {
  const int lane = threadIdx.x & 63;
  const int w = threadIdx.x >> 6;
  const size_t row = (size_t)blockIdx.x * 4 + w;
  float4 vals[4];
  float s = 0.f;
#pragma unroll
  for (int m = 0; m < 4; ++m) {
    vals[m] = *(const float4*)&o[row * D + m * 256 + lane * 4];
    s += (vals[m].x + vals[m].y) + (vals[m].z + vals[m].w);
  }
#pragma unroll
  for (int d = 1; d < 64; d <<= 1) s += __shfl_xor(s, d, 64);
  const float mu = s * (1.f / 1024.f);
  float vs = 0.f;
#pragma unroll
  for (int m = 0; m < 4; ++m) {
    float dx = vals[m].x - mu; vs += dx * dx;
    dx = vals[m].y - mu; vs += dx * dx;
    dx = vals[m].z - mu; vs += dx * dx;
    dx = vals[m].w - mu; vs += dx * dx;
  }
#pragma unroll
  for (int d = 1; d < 64; d <<= 1) vs += __shfl_xor(vs, d, 64);
  const float r = 1.f / sqrtf(vs * (1.f / 1024.f) + 1e-5f);
#pragma unroll
  for (int m = 0; m < 4; ++m) {
    const int dbase = m * 256 + lane * 4;
    float4 g4 = *(const float4*)&gamma[dbase];
    float4 b4 = *(const float4*)&betap[dbase];
    float4 y;
    y.x = (vals[m].x - mu) * r * g4.x + b4.x;
    y.y = (vals[m].y - mu) * r * g4.y + b4.y;
    y.z = (vals[m].z - mu) * r * g4.z + b4.z;
    y.w = (vals[m].w - mu) * r * g4.w + b4.w;
    *(float4*)&o[row * D + dbase] = y;
  }
}

// ---------------------------------------------------------------------------
extern "C" void kernel_launch(void* const* d_in, const int* in_sizes, int n_in,
                              void* d_out, int out_size, void* d_ws, size_t ws_size,
                              hipStream_t stream) {
  const float* x   = (const float*)d_in[0];
  const float* Wq  = (const float*)d_in[1];
  const float* Wk  = (const float*)d_in[2];
  const float* Wv  = (const float*)d_in[3];
  const float* Wb  = (const float*)d_in[4];
  const float* lng = (const float*)d_in[5];
  const float* lnb = (const float*)d_in[6];
  float* out = (float*)d_out;

  const size_t MB = 1ull << 20;
  char* wsb = (char*)d_ws;
  float* beta = (float*)wsb;                 // 64 KB
  short* Mg   = (short*)(wsb + 1 * MB);      // 2 MB
  short* Tg   = (short*)(wsb + 4 * MB);      // 2 MB
  short* WTq  = (short*)(wsb + 6 * MB);      // 2 MB
  short* WTk  = (short*)(wsb + 8 * MB);      // 2 MB
  short* WTv  = (short*)(wsb + 10 * MB);     // 2 MB
  short* xh   = (short*)(wsb + 16 * MB);     // 32 MB
  short* qh   = (short*)(wsb + 64 * MB);     // 32 MB
  short* kh   = (short*)(wsb + 96 * MB);
  short* vh   = (short*)(wsb + 128 * MB);
  short* kT   = (short*)(wsb + 160 * MB);

  const int N8 = (BATCH * LSEQ * D) / 8;
  const dim3 pg(128, 8);

  pack_bf16<<<2048, 256, 0, stream>>>(x, xh, N8);
  wtrans<<<dim3(16, 16), 256, 0, stream>>>(Wq, WTq);
  wtrans<<<dim3(16, 16), 256, 0, stream>>>(Wk, WTk);
  wtrans<<<dim3(16, 16), 256, 0, stream>>>(Wv, WTv);

  proj_mfma<<<pg, 256, 0, stream>>>(xh, WTq, qh, 0, 0.03125f);
  proj_mfma<<<pg, 256, 0, stream>>>(xh, WTk, kh, 1, 1.f);
  proj_mfma<<<pg, 256, 0, stream>>>(xh, WTv, vh, 2, 1.f);

  knormb<<<4096, 256, 0, stream>>>(kh);
  transpose_bf16<<<dim3(16, 32, 8), 256, 0, stream>>>(kh, kT);
  beta_kernel<<<4096, 256, 0, stream>>>(x, Wb, beta);

  precompute<<<256, 256, 0, stream>>>(qh, kh, beta, Mg, Tg);
  scan_chunked<<<dim3(8, 64), 256, 0, stream>>>(qh, kh, vh, kT, beta, Mg, Tg, out);
  ln_kernel<<<4096, 256, 0, stream>>>(out, lng, lnb);
}